// Round 1
// baseline (75.225 us; speedup 1.0000x reference)
//
#include <hip/hip_runtime.h>
#include <hip/hip_bf16.h>

#define C0   8192
#define C1   2048
#define CE0  131072
#define CE1  32768
#define CE2  2048

struct WS {
  int*   cnt;    // [0]=ne0 [1]=ne1 [2]=ne2 [3]=n0 [4]=n1
  float* s0;     // [C0]
  float* acc0;   // [C0*128]
  float* s1;     // [C1]
  float* acc1;   // [C1*128]
  int*   idx0;   // [N]
  int*   idx1;   // [N]
  float* wa;     // [16] : wa1[0..6], wa2[8..14]
  int*   list0;  // [C0]
  int*   list1;  // [C1]
  int*   e0s; int* e0d; float* e0v;
  int*   e1s; int* e1d; float* e1v;
  int*   e2s; float* e2v;
  float* f0; float* hh0; float* av10; float* av20;
  float* f1; float* hh1; float* av11; float* av21;
};

__device__ __forceinline__ float lrelu(float x, float a){ return x >= 0.f ? x : a * x; }
__device__ __forceinline__ float selu_f(float x){
  const float sc = 1.0507009873554805f, al = 1.6732632423543772f;
  return x > 0.f ? sc * x : sc * al * expm1f(x);
}
__device__ __forceinline__ void claim(int* idx, int* list, int* cnt, int cap, int node){
  if (atomicCAS(&idx[node], -1, -2) == -1){
    int slot = atomicAdd(cnt, 1);
    if (slot < cap){ list[slot] = node; idx[node] = slot; }
  }
}

__global__ void k_prep(WS w, const float* W0, const float* a1, const float* a2, int t){
  int j = threadIdx.x;
  if (j < 7){
    float sA = 0.f, sB = 0.f;
    for (int k = 0; k < 128; ++k){ float wv = W0[j*128 + k]; sA += wv * a1[k]; sB += wv * a2[k]; }
    w.wa[j] = sA; w.wa[8 + j] = sB;
  }
  if (j == 64){ w.idx1[t] = 0; w.list1[0] = t; w.cnt[4] = 1; }
}

__global__ void k_scan1(WS w, const int* ei, int E, int t){
  int i = blockIdx.x * blockDim.x + threadIdx.x;
  if (i >= E) return;
  int d = ei[E + i];
  if (d == t){
    int s = ei[i];
    int slot = atomicAdd(&w.cnt[2], 1);
    if (slot < CE2) w.e2s[slot] = s;
    claim(w.idx1, w.list1, &w.cnt[4], C1, s);
  }
}

__global__ void k_s1s0(WS w, int N){
  int u = blockIdx.x * blockDim.x + threadIdx.x;
  if (u < N && w.idx1[u] >= 0) claim(w.idx0, w.list0, &w.cnt[3], C0, u);
}

__global__ void k_scan2(WS w, const int* ei, int E){
  int i = blockIdx.x * blockDim.x + threadIdx.x;
  if (i >= E) return;
  int d = ei[E + i];
  if (w.idx1[d] >= 0){
    int s = ei[i];
    int slot = atomicAdd(&w.cnt[1], 1);
    if (slot < CE1){ w.e1s[slot] = s; w.e1d[slot] = d; }
    claim(w.idx0, w.list0, &w.cnt[3], C0, s);
  }
}

__global__ void k_scan3(WS w, const int* ei, int E){
  int i = blockIdx.x * blockDim.x + threadIdx.x;
  if (i >= E) return;
  int d = ei[E + i];
  if (w.idx0[d] >= 0){
    int s = ei[i];
    int slot = atomicAdd(&w.cnt[0], 1);
    if (slot < CE0){ w.e0s[slot] = s; w.e0d[slot] = d; }
  }
}

__global__ void k_e0_sum(WS w, const float* x){
  int i = blockIdx.x * blockDim.x + threadIdx.x;
  int ne = min(w.cnt[0], CE0);
  if (i >= ne) return;
  int s = w.e0s[i], d = w.e0d[i];
  float f = 0.f;
  for (int j = 0; j < 7; ++j) f += x[s*7 + j] * w.wa[j] + x[d*7 + j] * w.wa[8 + j];
  float e = expf(lrelu(f, 0.2f));
  w.e0v[i] = e;
  atomicAdd(&w.s0[w.idx0[d]], e);
}

__global__ void k_e0_agg(WS w, const float* x, const float* W0){
  int ne = min(w.cnt[0], CE0);
  int k = threadIdx.x;
  for (int i = blockIdx.x; i < ne; i += gridDim.x){
    int s = w.e0s[i], d = w.e0d[i];
    int id = w.idx0[d];
    float coef = w.e0v[i] / (w.s0[id] + 1e-9f);
    float h = 0.f;
    for (int j = 0; j < 7; ++j) h += x[s*7 + j] * W0[j*128 + k];
    atomicAdd(&w.acc0[id*128 + k], coef * h);
  }
}

__global__ void k_n0_fin(WS w, const float* x, const float* Wr0, const float* b0){
  int n0 = min(w.cnt[3], C0);
  int k = threadIdx.x;
  for (int b = blockIdx.x; b < n0; b += gridDim.x){
    int u = w.list0[b];
    float res = 0.f;
    for (int j = 0; j < 7; ++j) res += x[u*7 + j] * Wr0[j*128 + k];
    w.f0[b*128 + k] = selu_f(w.acc0[b*128 + k] + b0[k] + res);
  }
}

__global__ void k_hh(const float* feat, float* hh, float* av1o, float* av2o,
                     const float* Wm, const float* a1, const float* a2,
                     const int* cntp, int cap){
  __shared__ float sf[128];
  __shared__ float red[128];
  int n = min(*cntp, cap);
  int k = threadIdx.x;
  for (int b = blockIdx.x; b < n; b += gridDim.x){
    sf[k] = feat[b*128 + k];
    __syncthreads();
    float acc = 0.f;
    for (int j = 0; j < 128; ++j) acc += sf[j] * Wm[j*128 + k];
    hh[b*128 + k] = acc;
    red[k] = acc * a1[k];
    __syncthreads();
    for (int st = 64; st > 0; st >>= 1){ if (k < st) red[k] += red[k + st]; __syncthreads(); }
    if (k == 0) av1o[b] = red[0];
    __syncthreads();
    red[k] = acc * a2[k];
    __syncthreads();
    for (int st = 64; st > 0; st >>= 1){ if (k < st) red[k] += red[k + st]; __syncthreads(); }
    if (k == 0) av2o[b] = red[0];
    __syncthreads();
  }
}

__global__ void k_e1_sum(WS w){
  int i = blockIdx.x * blockDim.x + threadIdx.x;
  int ne = min(w.cnt[1], CE1);
  if (i >= ne) return;
  int s = w.e1s[i], d = w.e1d[i];
  int i0s = w.idx0[s];
  if (i0s < 0){ w.e1v[i] = 0.f; return; }
  float f = w.av10[i0s] + w.av20[w.idx0[d]];
  float e = expf(lrelu(f, 0.2f));
  w.e1v[i] = e;
  atomicAdd(&w.s1[w.idx1[d]], e);
}

__global__ void k_e1_agg(WS w){
  int ne = min(w.cnt[1], CE1);
  int k = threadIdx.x;
  for (int i = blockIdx.x; i < ne; i += gridDim.x){
    int s = w.e1s[i], d = w.e1d[i];
    int i0s = w.idx0[s];
    if (i0s < 0) continue;
    int i1 = w.idx1[d];
    float coef = w.e1v[i] / (w.s1[i1] + 1e-9f);
    atomicAdd(&w.acc1[i1*128 + k], coef * w.hh0[i0s*128 + k]);
  }
}

__global__ void k_n1_fin(WS w, const float* bf0){
  int n1 = min(w.cnt[4], C1);
  int k = threadIdx.x;
  for (int b = blockIdx.x; b < n1; b += gridDim.x){
    int u = w.list1[b];
    int i0 = w.idx0[u];
    if (i0 < 0) continue;
    float f0v = w.f0[i0*128 + k];
    float lo = selu_f(w.acc1[b*128 + k] + bf0[k] + f0v);
    w.f1[b*128 + k] = f0v + lo;
  }
}

__global__ void k_l2(WS w, const float* bf1, const float* Wfc, const float* bfc,
                     float* out, int t){
  __shared__ float red[128];
  int k = threadIdx.x;
  int ne = min(w.cnt[2], CE2);
  float local = 0.f;
  for (int i = k; i < ne; i += 128){
    int s = w.e2s[i];
    int i1s = w.idx1[s];
    float e = 0.f;
    if (i1s >= 0){
      float f = w.av11[i1s] + w.av21[0];   // idx1[t] == 0
      e = expf(lrelu(f, 0.2f));
    }
    w.e2v[i] = e;
    local += e;
  }
  red[k] = local;
  __syncthreads();
  for (int st = 64; st > 0; st >>= 1){ if (k < st) red[k] += red[k + st]; __syncthreads(); }
  float s2 = red[0];
  __syncthreads();
  float acc = 0.f;
  for (int i = 0; i < ne; ++i){
    int i1s = w.idx1[w.e2s[i]];
    if (i1s < 0) continue;
    acc += (w.e2v[i] / (s2 + 1e-9f)) * w.hh1[i1s*128 + k];
  }
  float f1v = w.f1[k];                      // slot 0 is node t
  float lo = selu_f(acc + bf1[k] + f1v);
  float fin = f1v + lo;
  red[k] = fin * Wfc[k];
  __syncthreads();
  for (int st = 64; st > 0; st >>= 1){ if (k < st) red[k] += red[k + st]; __syncthreads(); }
  if (k == 0) out[0] = lrelu(red[0] + bfc[0], 0.01f);
}

extern "C" void kernel_launch(void* const* d_in, const int* in_sizes, int n_in,
                              void* d_out, int out_size, void* d_ws, size_t ws_size,
                              hipStream_t stream){
  (void)n_in; (void)out_size;
  const float* x    = (const float*)d_in[0];
  const int*   ei   = (const int*)  d_in[1];
  const float* W0   = (const float*)d_in[2];
  const float* a1_0 = (const float*)d_in[3];
  const float* a2_0 = (const float*)d_in[4];
  const float* b0   = (const float*)d_in[5];
  const float* Wr0  = (const float*)d_in[6];
  // d_in[7..9] (Wa0,ba0,ua0) unused: SimpleAtt over T=1 is identity
  const float* Wf   = (const float*)d_in[10];
  const float* a1f  = (const float*)d_in[11];
  const float* a2f  = (const float*)d_in[12];
  const float* bf   = (const float*)d_in[13];
  // d_in[14..16] (Waf,baf,uaf) unused: identity
  const float* Wfc  = (const float*)d_in[17];
  const float* bfc  = (const float*)d_in[18];
  float* out = (float*)d_out;

  int N = in_sizes[0] / 7;
  int E = in_sizes[1] / 2;
  int t = N - 1;

  char* p = (char*)d_ws;
  auto alloc = [&](size_t bytes) -> void* {
    void* r = (void*)p;
    p += (bytes + 255) & ~(size_t)255;
    return r;
  };
  WS w;
  // ---- zero-initialized zone ----
  w.cnt  = (int*)  alloc(64);
  w.s0   = (float*)alloc(sizeof(float)*C0);
  w.acc0 = (float*)alloc(sizeof(float)*(size_t)C0*128);
  w.s1   = (float*)alloc(sizeof(float)*C1);
  w.acc1 = (float*)alloc(sizeof(float)*(size_t)C1*128);
  size_t zbytes = (size_t)(p - (char*)d_ws);
  // ---- 0xFF zone (idx maps -> -1) ----
  char* fbase = p;
  w.idx0 = (int*)alloc(sizeof(int)*(size_t)N);
  w.idx1 = (int*)alloc(sizeof(int)*(size_t)N);
  size_t fbytes = (size_t)(p - fbase);
  // ---- uninitialized (written before read) ----
  w.wa    = (float*)alloc(sizeof(float)*16);
  w.list0 = (int*)alloc(sizeof(int)*C0);
  w.list1 = (int*)alloc(sizeof(int)*C1);
  w.e0s = (int*)alloc(sizeof(int)*CE0);
  w.e0d = (int*)alloc(sizeof(int)*CE0);
  w.e0v = (float*)alloc(sizeof(float)*CE0);
  w.e1s = (int*)alloc(sizeof(int)*CE1);
  w.e1d = (int*)alloc(sizeof(int)*CE1);
  w.e1v = (float*)alloc(sizeof(float)*CE1);
  w.e2s = (int*)alloc(sizeof(int)*CE2);
  w.e2v = (float*)alloc(sizeof(float)*CE2);
  w.f0  = (float*)alloc(sizeof(float)*(size_t)C0*128);
  w.hh0 = (float*)alloc(sizeof(float)*(size_t)C0*128);
  w.av10= (float*)alloc(sizeof(float)*C0);
  w.av20= (float*)alloc(sizeof(float)*C0);
  w.f1  = (float*)alloc(sizeof(float)*(size_t)C1*128);
  w.hh1 = (float*)alloc(sizeof(float)*(size_t)C1*128);
  w.av11= (float*)alloc(sizeof(float)*C1);
  w.av21= (float*)alloc(sizeof(float)*C1);
  size_t need = (size_t)(p - (char*)d_ws);
  if (need > ws_size) return;  // workspace too small; bail (expected ~18.5 MB)

  hipMemsetAsync(d_ws, 0, zbytes, stream);
  hipMemsetAsync(fbase, 0xFF, fbytes, stream);

  int eb = (E + 255) / 256, nb = (N + 255) / 256;
  k_prep <<<1, 128, 0, stream>>>(w, W0, a1_0, a2_0, t);
  k_scan1<<<eb, 256, 0, stream>>>(w, ei, E, t);
  k_s1s0 <<<nb, 256, 0, stream>>>(w, N);
  k_scan2<<<eb, 256, 0, stream>>>(w, ei, E);
  k_scan3<<<eb, 256, 0, stream>>>(w, ei, E);
  k_e0_sum<<<CE0/256, 256, 0, stream>>>(w, x);
  k_e0_agg<<<1024, 128, 0, stream>>>(w, x, W0);
  k_n0_fin<<<1024, 128, 0, stream>>>(w, x, Wr0, b0);
  k_hh<<<1024, 128, 0, stream>>>(w.f0, w.hh0, w.av10, w.av20, Wf, a1f, a2f, w.cnt + 3, C0);
  k_e1_sum<<<CE1/256, 256, 0, stream>>>(w);
  k_e1_agg<<<512, 128, 0, stream>>>(w);
  k_n1_fin<<<256, 128, 0, stream>>>(w, bf);
  k_hh<<<256, 128, 0, stream>>>(w.f1, w.hh1, w.av11, w.av21, Wf + 128*128, a1f + 128, a2f + 128, w.cnt + 4, C1);
  k_l2<<<1, 128, 0, stream>>>(w, bf + 128, Wfc, bfc, out, t);
}

// Round 2
// 71.932 us; speedup vs baseline: 1.0458x; 1.0458x over previous
//
#include <hip/hip_runtime.h>
#include <hip/hip_bf16.h>

#define C0   8192
#define C1   2048
#define CE0  131072
#define CE1  32768
#define CE2  2048

struct WS {
  int*   cnt;    // [0]=ne0 [1]=ne1 [2]=ne2 [3]=n0 [4]=n1
  float* s0;     // [C0]
  float* acc0;   // [C0*128]
  float* s1;     // [C1]
  float* acc1;   // [C1*128]
  int*   idx0;   // [N]
  int*   idx1;   // [N]
  float* wa;     // [16] : wa1[0..6], wa2[8..14]
  int*   list0;  // [C0]
  int*   list1;  // [C1]
  int*   e0s; int* e0d; float* e0v;
  int*   e1s; int* e1d; float* e1v;
  int*   e2s; float* e2v;
  float* f0; float* hh0; float* av10; float* av20;
  float* f1; float* hh1; float* av11; float* av21;
};

__device__ __forceinline__ float lrelu(float x, float a){ return x >= 0.f ? x : a * x; }
__device__ __forceinline__ float selu_f(float x){
  const float sc = 1.0507009873554805f, al = 1.6732632423543772f;
  return x > 0.f ? sc * x : sc * al * expm1f(x);
}
// claim a node into the compact list; zero its softmax-denominator and
// 128-wide accumulator slot at claim time (replaces the 5.2 MB memset).
__device__ __forceinline__ void claim(int* idx, int* list, int* cnt, int cap, int node,
                                      float* s, float* acc){
  if (atomicCAS(&idx[node], -1, -2) == -1){
    int slot = atomicAdd(cnt, 1);
    if (slot < cap){
      list[slot] = node;
      s[slot] = 0.f;
      float* a = acc + (size_t)slot * 128;
      #pragma unroll 4
      for (int k = 0; k < 128; ++k) a[k] = 0.f;
      idx[node] = slot;
    }
  }
}

// init: idx maps to -1 (idx1[t]=0), cnt, wa precompute, slot-0 of level-1 accs
__global__ void k_init(WS w, const float* W0, const float* a1, const float* a2,
                       int N, int t){
  int u = blockIdx.x * blockDim.x + threadIdx.x;
  if (u < N){
    w.idx0[u] = -1;
    w.idx1[u] = (u == t) ? 0 : -1;
  }
  if (blockIdx.x == 0){
    int j = threadIdx.x;
    if (j < 7){
      float sA = 0.f, sB = 0.f;
      for (int k = 0; k < 128; ++k){ float wv = W0[j*128 + k]; sA += wv * a1[k]; sB += wv * a2[k]; }
      w.wa[j] = sA; w.wa[8 + j] = sB;
    }
    if (j >= 16 && j < 21) w.cnt[j - 16] = (j - 16 == 4) ? 1 : 0;
    if (j == 24) w.list1[0] = t;
    if (j < 128) w.acc1[j] = 0.f;   // slot 0 (node t) accumulator
    if (j == 140) w.s1[0] = 0.f;
  }
}

__global__ void k_scan1(WS w, const int* ei, int E, int t){
  int i = blockIdx.x * blockDim.x + threadIdx.x;
  if (i >= E) return;
  int d = ei[E + i];
  if (d == t){
    int s = ei[i];
    int slot = atomicAdd(&w.cnt[2], 1);
    if (slot < CE2) w.e2s[slot] = s;
    claim(w.idx1, w.list1, &w.cnt[4], C1, s, w.s1, w.acc1);
  }
}

__global__ void k_s1s0(WS w, int N){
  int u = blockIdx.x * blockDim.x + threadIdx.x;
  if (u < N && w.idx1[u] >= 0)
    claim(w.idx0, w.list0, &w.cnt[3], C0, u, w.s0, w.acc0);
}

__global__ void k_scan2(WS w, const int* ei, int E){
  int i = blockIdx.x * blockDim.x + threadIdx.x;
  if (i >= E) return;
  int d = ei[E + i];
  if (w.idx1[d] >= 0){
    int s = ei[i];
    int slot = atomicAdd(&w.cnt[1], 1);
    if (slot < CE1){ w.e1s[slot] = s; w.e1d[slot] = d; }
    claim(w.idx0, w.list0, &w.cnt[3], C0, s, w.s0, w.acc0);
  }
}

__global__ void k_scan3(WS w, const int* ei, int E){
  int i = blockIdx.x * blockDim.x + threadIdx.x;
  if (i >= E) return;
  int d = ei[E + i];
  if (w.idx0[d] >= 0){
    int s = ei[i];
    int slot = atomicAdd(&w.cnt[0], 1);
    if (slot < CE0){ w.e0s[slot] = s; w.e0d[slot] = d; }
  }
}

__global__ void k_e0_sum(WS w, const float* x){
  int ne = min(w.cnt[0], CE0);
  for (int i = blockIdx.x * blockDim.x + threadIdx.x; i < ne; i += gridDim.x * blockDim.x){
    int s = w.e0s[i], d = w.e0d[i];
    float f = 0.f;
    for (int j = 0; j < 7; ++j) f += x[s*7 + j] * w.wa[j] + x[d*7 + j] * w.wa[8 + j];
    float e = expf(lrelu(f, 0.2f));
    w.e0v[i] = e;
    atomicAdd(&w.s0[w.idx0[d]], e);
  }
}

__global__ void k_e0_agg(WS w, const float* x, const float* W0){
  int ne = min(w.cnt[0], CE0);
  int k = threadIdx.x;
  for (int i = blockIdx.x; i < ne; i += gridDim.x){
    int s = w.e0s[i], d = w.e0d[i];
    int id = w.idx0[d];
    float coef = w.e0v[i] / (w.s0[id] + 1e-9f);
    float h = 0.f;
    for (int j = 0; j < 7; ++j) h += x[s*7 + j] * W0[j*128 + k];
    atomicAdd(&w.acc0[(size_t)id*128 + k], coef * h);
  }
}

__global__ void k_n0_fin(WS w, const float* x, const float* Wr0, const float* b0){
  int n0 = min(w.cnt[3], C0);
  int k = threadIdx.x;
  for (int b = blockIdx.x; b < n0; b += gridDim.x){
    int u = w.list0[b];
    float res = 0.f;
    for (int j = 0; j < 7; ++j) res += x[u*7 + j] * Wr0[j*128 + k];
    w.f0[(size_t)b*128 + k] = selu_f(w.acc0[(size_t)b*128 + k] + b0[k] + res);
  }
}

__global__ void k_hh(const float* feat, float* hh, float* av1o, float* av2o,
                     const float* Wm, const float* a1, const float* a2,
                     const int* cntp, int cap){
  __shared__ float sf[128];
  __shared__ float red[128];
  int n = min(*cntp, cap);
  int k = threadIdx.x;
  for (int b = blockIdx.x; b < n; b += gridDim.x){
    sf[k] = feat[(size_t)b*128 + k];
    __syncthreads();
    float acc = 0.f;
    for (int j = 0; j < 128; ++j) acc += sf[j] * Wm[j*128 + k];
    hh[(size_t)b*128 + k] = acc;
    red[k] = acc * a1[k];
    __syncthreads();
    for (int st = 64; st > 0; st >>= 1){ if (k < st) red[k] += red[k + st]; __syncthreads(); }
    if (k == 0) av1o[b] = red[0];
    __syncthreads();
    red[k] = acc * a2[k];
    __syncthreads();
    for (int st = 64; st > 0; st >>= 1){ if (k < st) red[k] += red[k + st]; __syncthreads(); }
    if (k == 0) av2o[b] = red[0];
    __syncthreads();
  }
}

__global__ void k_e1_sum(WS w){
  int ne = min(w.cnt[1], CE1);
  for (int i = blockIdx.x * blockDim.x + threadIdx.x; i < ne; i += gridDim.x * blockDim.x){
    int s = w.e1s[i], d = w.e1d[i];
    int i0s = w.idx0[s];
    if (i0s < 0){ w.e1v[i] = 0.f; continue; }
    float f = w.av10[i0s] + w.av20[w.idx0[d]];
    float e = expf(lrelu(f, 0.2f));
    w.e1v[i] = e;
    atomicAdd(&w.s1[w.idx1[d]], e);
  }
}

__global__ void k_e1_agg(WS w){
  int ne = min(w.cnt[1], CE1);
  int k = threadIdx.x;
  for (int i = blockIdx.x; i < ne; i += gridDim.x){
    int s = w.e1s[i], d = w.e1d[i];
    int i0s = w.idx0[s];
    if (i0s < 0) continue;
    int i1 = w.idx1[d];
    float coef = w.e1v[i] / (w.s1[i1] + 1e-9f);
    atomicAdd(&w.acc1[(size_t)i1*128 + k], coef * w.hh0[(size_t)i0s*128 + k]);
  }
}

__global__ void k_n1_fin(WS w, const float* bf0){
  int n1 = min(w.cnt[4], C1);
  int k = threadIdx.x;
  for (int b = blockIdx.x; b < n1; b += gridDim.x){
    int u = w.list1[b];
    int i0 = w.idx0[u];
    if (i0 < 0) continue;
    float f0v = w.f0[(size_t)i0*128 + k];
    float lo = selu_f(w.acc1[(size_t)b*128 + k] + bf0[k] + f0v);
    w.f1[(size_t)b*128 + k] = f0v + lo;
  }
}

__global__ void k_l2(WS w, const float* bf1, const float* Wfc, const float* bfc,
                     float* out, int t){
  __shared__ float red[128];
  int k = threadIdx.x;
  int ne = min(w.cnt[2], CE2);
  float local = 0.f;
  for (int i = k; i < ne; i += 128){
    int s = w.e2s[i];
    int i1s = w.idx1[s];
    float e = 0.f;
    if (i1s >= 0){
      float f = w.av11[i1s] + w.av21[0];   // idx1[t] == 0
      e = expf(lrelu(f, 0.2f));
    }
    w.e2v[i] = e;
    local += e;
  }
  red[k] = local;
  __syncthreads();
  for (int st = 64; st > 0; st >>= 1){ if (k < st) red[k] += red[k + st]; __syncthreads(); }
  float s2 = red[0];
  __syncthreads();
  float acc = 0.f;
  for (int i = 0; i < ne; ++i){
    int i1s = w.idx1[w.e2s[i]];
    if (i1s < 0) continue;
    acc += (w.e2v[i] / (s2 + 1e-9f)) * w.hh1[(size_t)i1s*128 + k];
  }
  float f1v = w.f1[k];                      // slot 0 is node t
  float lo = selu_f(acc + bf1[k] + f1v);
  float fin = f1v + lo;
  red[k] = fin * Wfc[k];
  __syncthreads();
  for (int st = 64; st > 0; st >>= 1){ if (k < st) red[k] += red[k + st]; __syncthreads(); }
  if (k == 0) out[0] = lrelu(red[0] + bfc[0], 0.01f);
}

extern "C" void kernel_launch(void* const* d_in, const int* in_sizes, int n_in,
                              void* d_out, int out_size, void* d_ws, size_t ws_size,
                              hipStream_t stream){
  (void)n_in; (void)out_size;
  const float* x    = (const float*)d_in[0];
  const int*   ei   = (const int*)  d_in[1];
  const float* W0   = (const float*)d_in[2];
  const float* a1_0 = (const float*)d_in[3];
  const float* a2_0 = (const float*)d_in[4];
  const float* b0   = (const float*)d_in[5];
  const float* Wr0  = (const float*)d_in[6];
  // d_in[7..9] (Wa0,ba0,ua0) unused: SimpleAtt over T=1 is identity
  const float* Wf   = (const float*)d_in[10];
  const float* a1f  = (const float*)d_in[11];
  const float* a2f  = (const float*)d_in[12];
  const float* bf   = (const float*)d_in[13];
  // d_in[14..16] (Waf,baf,uaf) unused: identity
  const float* Wfc  = (const float*)d_in[17];
  const float* bfc  = (const float*)d_in[18];
  float* out = (float*)d_out;

  int N = in_sizes[0] / 7;
  int E = in_sizes[1] / 2;
  int t = N - 1;

  char* p = (char*)d_ws;
  auto alloc = [&](size_t bytes) -> void* {
    void* r = (void*)p;
    p += (bytes + 255) & ~(size_t)255;
    return r;
  };
  WS w;
  w.cnt  = (int*)  alloc(64);
  w.s0   = (float*)alloc(sizeof(float)*C0);
  w.acc0 = (float*)alloc(sizeof(float)*(size_t)C0*128);
  w.s1   = (float*)alloc(sizeof(float)*C1);
  w.acc1 = (float*)alloc(sizeof(float)*(size_t)C1*128);
  w.idx0 = (int*)alloc(sizeof(int)*(size_t)N);
  w.idx1 = (int*)alloc(sizeof(int)*(size_t)N);
  w.wa    = (float*)alloc(sizeof(float)*16);
  w.list0 = (int*)alloc(sizeof(int)*C0);
  w.list1 = (int*)alloc(sizeof(int)*C1);
  w.e0s = (int*)alloc(sizeof(int)*CE0);
  w.e0d = (int*)alloc(sizeof(int)*CE0);
  w.e0v = (float*)alloc(sizeof(float)*CE0);
  w.e1s = (int*)alloc(sizeof(int)*CE1);
  w.e1d = (int*)alloc(sizeof(int)*CE1);
  w.e1v = (float*)alloc(sizeof(float)*CE1);
  w.e2s = (int*)alloc(sizeof(int)*CE2);
  w.e2v = (float*)alloc(sizeof(float)*CE2);
  w.f0  = (float*)alloc(sizeof(float)*(size_t)C0*128);
  w.hh0 = (float*)alloc(sizeof(float)*(size_t)C0*128);
  w.av10= (float*)alloc(sizeof(float)*C0);
  w.av20= (float*)alloc(sizeof(float)*C0);
  w.f1  = (float*)alloc(sizeof(float)*(size_t)C1*128);
  w.hh1 = (float*)alloc(sizeof(float)*(size_t)C1*128);
  w.av11= (float*)alloc(sizeof(float)*C1);
  w.av21= (float*)alloc(sizeof(float)*C1);
  size_t need = (size_t)(p - (char*)d_ws);
  if (need > ws_size) return;  // workspace too small (expected ~18.5 MB)

  int eb = (E + 255) / 256, nb = (N + 255) / 256;
  k_init <<<nb, 256, 0, stream>>>(w, W0, a1_0, a2_0, N, t);
  k_scan1<<<eb, 256, 0, stream>>>(w, ei, E, t);
  k_s1s0 <<<nb, 256, 0, stream>>>(w, N);
  k_scan2<<<eb, 256, 0, stream>>>(w, ei, E);
  k_scan3<<<eb, 256, 0, stream>>>(w, ei, E);
  k_e0_sum<<<64, 256, 0, stream>>>(w, x);
  k_e0_agg<<<256, 128, 0, stream>>>(w, x, W0);
  k_n0_fin<<<256, 128, 0, stream>>>(w, x, Wr0, b0);
  k_hh<<<256, 128, 0, stream>>>(w.f0, w.hh0, w.av10, w.av20, Wf, a1f, a2f, w.cnt + 3, C0);
  k_e1_sum<<<32, 256, 0, stream>>>(w);
  k_e1_agg<<<128, 128, 0, stream>>>(w);
  k_n1_fin<<<64, 128, 0, stream>>>(w, bf);
  k_hh<<<64, 128, 0, stream>>>(w.f1, w.hh1, w.av11, w.av21, Wf + 128*128, a1f + 128, a2f + 128, w.cnt + 4, C1);
  k_l2<<<1, 128, 0, stream>>>(w, bf + 128, Wfc, bfc, out, t);
}